// Round 9
// baseline (280.043 us; speedup 1.0000x reference)
//
#include <hip/hip_runtime.h>
#include <hip/hip_bf16.h>
#include <hip/hip_cooperative_groups.h>
#include <math.h>

namespace cg = cooperative_groups;

#define EPSLN 1e-5f

typedef __attribute__((ext_vector_type(8))) short short8;
typedef __attribute__((ext_vector_type(4))) float f32x4;
typedef __attribute__((ext_vector_type(4))) unsigned short u16x4;

__device__ inline unsigned short f2bf(float f){
  unsigned int u = __float_as_uint(f);
  u += 0x7fffu + ((u >> 16) & 1u);
  return (unsigned short)(u >> 16);
}

// butterfly: all 64 lanes end with the total
__device__ inline float wredb(float v){
  #pragma unroll
  for(int o = 1; o < 64; o <<= 1) v += __shfl_xor(v, o, 64);
  return v;
}

// plain tree reduce, lane 0 has result
__device__ inline float wred(float v){
  #pragma unroll
  for(int o = 32; o > 0; o >>= 1) v += __shfl_down(v, o, 64);
  return v;
}

// ---------------------------------------------------------------------------
// K_A "prep": blocks [0,256): LN1 colsum partial per block -> part[blk][512]
//             blocks [256,2304): f32->bf16 conversion of fc1_w, fc2_w
// ---------------------------------------------------------------------------
__global__ __launch_bounds__(256) void prep(
    const float* __restrict__ x, const float* __restrict__ ln1w,
    const float* __restrict__ ln1b, const float* __restrict__ fc1w,
    const float* __restrict__ fc2w, float* __restrict__ part,
    unsigned short* __restrict__ w1b, unsigned short* __restrict__ w2b)
{
  __shared__ float red[4][512];
  const int tid = threadIdx.x;
  const int blk = blockIdx.x;
  if(blk < 256){
    const int lane = tid & 63, wv = tid >> 6;
    const int b = blk >> 6, local = blk & 63;
    const f32x4* wp = (const f32x4*)ln1w;
    const f32x4* bp = (const f32x4*)ln1b;
    f32x4 w1 = wp[lane * 2], w2 = wp[lane * 2 + 1];
    f32x4 b1 = bp[lane * 2], b2 = bp[lane * 2 + 1];
    f32x4 a1 = (f32x4)(0.f), a2 = (f32x4)(0.f);
    const int r0 = local * 16 + wv * 4;
    for(int i = 0; i < 4; i++){
      const size_t row = (size_t)b * 1024 + r0 + i;
      const f32x4* xr = (const f32x4*)(x + row * 512);
      f32x4 v1 = xr[lane * 2], v2 = xr[lane * 2 + 1];
      float s = v1[0]+v1[1]+v1[2]+v1[3] + v2[0]+v2[1]+v2[2]+v2[3];
      float q = v1[0]*v1[0]+v1[1]*v1[1]+v1[2]*v1[2]+v1[3]*v1[3]
              + v2[0]*v2[0]+v2[1]*v2[1]+v2[2]*v2[2]+v2[3]*v2[3];
      s = wredb(s); q = wredb(q);
      float mu = s * (1.f / 512.f);
      float rs = rsqrtf(q * (1.f / 512.f) - mu * mu + EPSLN);
      #pragma unroll
      for(int j = 0; j < 4; j++){
        a1[j] += (v1[j] - mu) * rs * w1[j] + b1[j];
        a2[j] += (v2[j] - mu) * rs * w2[j] + b2[j];
      }
    }
    #pragma unroll
    for(int j = 0; j < 4; j++){
      red[wv][lane * 8 + j]     = a1[j];
      red[wv][lane * 8 + 4 + j] = a2[j];
    }
    __syncthreads();
    #pragma unroll
    for(int c = tid; c < 512; c += 256)
      part[(size_t)blk * 512 + c] = red[0][c] + red[1][c] + red[2][c] + red[3][c];
  } else {
    const int w = blk - 256;
    const float* src = (w < 1024) ? fc1w : fc2w;
    unsigned short* dst = (w < 1024) ? w1b : w2b;
    const int off = ((w & 1023) << 10) + tid * 4;
    f32x4 v = *(const f32x4*)(src + off);
    u16x4 r;
    #pragma unroll
    for(int j = 0; j < 4; j++) r[j] = f2bf(v[j]);
    *(u16x4*)(dst + off) = r;
  }
}

// ---------------------------------------------------------------------------
// K_B "attn_mid" (COOPERATIVE, 1024 blocks x 256 threads, 2 grid syncs):
//  phase1 (blocks<128): reduce 64 partials -> cs[512]; vmean = cs.Wv/1024+bv
//  phase2 (blocks<512): arow = vmean.outw + outb
//  phase3 (all 1024):   xl2 = LN2(x + arow) as bf16 (4 rows/block)
// ---------------------------------------------------------------------------
__global__ __launch_bounds__(256) void attn_mid(
    const float* __restrict__ part, const float* __restrict__ qkvw,
    const float* __restrict__ qkvb, const float* __restrict__ outw,
    const float* __restrict__ outb, const float* __restrict__ x,
    const float* __restrict__ ln2w, const float* __restrict__ ln2b,
    float* __restrict__ vmean, float* __restrict__ arow,
    unsigned short* __restrict__ xl2)
{
  cg::grid_group grid = cg::this_grid();
  const int tid = threadIdx.x, lane = tid & 63, wv = tid >> 6;

  // ---- phase 1: colsum reduce + Wv matvec (128 blocks) ----
  if(blockIdx.x < 128){
    __shared__ float cs[512];
    const int b = blockIdx.x >> 5;
    const int nb = (blockIdx.x & 31) * 16;
    #pragma unroll
    for(int c = tid; c < 512; c += 256){
      float s = 0.f;
      const float* pp = part + (size_t)(b * 64) * 512 + c;
      #pragma unroll 8
      for(int p = 0; p < 64; p++) s += pp[(size_t)p * 512];
      cs[c] = s;
    }
    __syncthreads();
    const f32x4* c4 = (const f32x4*)cs;
    f32x4 v1 = c4[lane * 2], v2 = c4[lane * 2 + 1];
    #pragma unroll
    for(int o = 0; o < 4; o++){
      int n = nb + wv * 4 + o;
      const f32x4* wr = (const f32x4*)(qkvw + (size_t)(1024 + n) * 512);
      f32x4 w1 = wr[lane * 2], w2 = wr[lane * 2 + 1];
      float s = 0.f;
      #pragma unroll
      for(int i = 0; i < 4; i++) s += v1[i] * w1[i] + v2[i] * w2[i];
      s = wred(s);
      if(lane == 0) vmean[b * 512 + n] = s * (1.f / 1024.f) + qkvb[1024 + n];
    }
  }
  grid.sync();

  // ---- phase 2: out-proj matvec (512 blocks, wave per output) ----
  if(blockIdx.x < 512){
    int gw = blockIdx.x * 4 + wv;
    int b = gw >> 9, n = gw & 511;
    const f32x4* vr = (const f32x4*)(vmean + ((size_t)b << 9));
    const f32x4* wr = (const f32x4*)(outw + ((size_t)n << 9));
    f32x4 v1 = vr[lane * 2], v2 = vr[lane * 2 + 1];
    f32x4 w1 = wr[lane * 2], w2 = wr[lane * 2 + 1];
    float s = 0.f;
    #pragma unroll
    for(int i = 0; i < 4; i++) s += v1[i] * w1[i] + v2[i] * w2[i];
    s = wred(s);
    if(lane == 0) arow[gw] = s + outb[n];
  }
  grid.sync();

  // ---- phase 3: x2 = x + arow ; xl2 = LN2(x2) bf16 (1024 blocks, 4 rows) ----
  {
    const size_t row = (size_t)blockIdx.x * 4 + wv;
    const int b = (int)(row >> 10);
    const f32x4* xr = (const f32x4*)(x + row * 512);
    const f32x4* ar = (const f32x4*)(arow + ((size_t)b << 9));
    f32x4 v1 = xr[lane * 2], v2 = xr[lane * 2 + 1];
    f32x4 r1 = ar[lane * 2], r2 = ar[lane * 2 + 1];
    #pragma unroll
    for(int j = 0; j < 4; j++){ v1[j] += r1[j]; v2[j] += r2[j]; }
    float s = v1[0]+v1[1]+v1[2]+v1[3] + v2[0]+v2[1]+v2[2]+v2[3];
    float q = v1[0]*v1[0]+v1[1]*v1[1]+v1[2]*v1[2]+v1[3]*v1[3]
            + v2[0]*v2[0]+v2[1]*v2[1]+v2[2]*v2[2]+v2[3]*v2[3];
    s = wredb(s); q = wredb(q);
    float mu = s * (1.f / 512.f);
    float rs = rsqrtf(q * (1.f / 512.f) - mu * mu + EPSLN);
    const f32x4* wp = (const f32x4*)ln2w;
    const f32x4* bp = (const f32x4*)ln2b;
    f32x4 w1 = wp[lane * 2], w2 = wp[lane * 2 + 1];
    f32x4 b1 = bp[lane * 2], b2 = bp[lane * 2 + 1];
    u16x4 o1, o2;
    #pragma unroll
    for(int j = 0; j < 4; j++){
      o1[j] = f2bf((v1[j] - mu) * rs * w1[j] + b1[j]);
      o2[j] = f2bf((v2[j] - mu) * rs * w2[j] + b2[j]);
    }
    u16x4* op = (u16x4*)(xl2 + row * 512 + lane * 8);
    op[0] = o1; op[1] = o2;
  }
}

// ---------------------------------------------------------------------------
// K_E/K_F: bf16 MFMA GEMM, 2-phase double-buffered, parametric BK.
// LDS layout per matrix: [BK/32 k-slices][rows][32 shorts].
// 4 waves 2x2; wave tile (BM/2) x (BN/2); MI=BM/32, NI=BN/32.
// EPI==0: gelu -> bf16 ; EPI==1: + resx + resrow -> f32
// ---------------------------------------------------------------------------
__device__ inline void gld_lds16(const void* g, void* l){
  __builtin_amdgcn_global_load_lds(
      (const __attribute__((address_space(1))) void*)g,
      (__attribute__((address_space(3))) void*)l, 16, 0, 0);
}

template<int BM, int BN, int BK, int EPI>
__global__ __launch_bounds__(256, 2) void gemm_bt(
    const unsigned short* __restrict__ A, const unsigned short* __restrict__ W,
    const float* __restrict__ bias, const float* __restrict__ resx,
    const float* __restrict__ resrow, void* __restrict__ outp,
    int M, int N, int K)
{
  constexpr int MI = BM / 32, NI = BN / 32;
  constexpr int KS = BK / 32;                    // k-slices of 32
  constexpr int PA = BM * BK / 2048;             // staging passes (4KB each)
  constexpr int PB = BN * BK / 2048;
  constexpr int RPA = BM / 64, RPB = BN / 64;    // 64-row chunks per k-slice
  __shared__ __align__(16) unsigned short sA[2][BM * BK];
  __shared__ __align__(16) unsigned short sB[2][BN * BK];
  const int tid = threadIdx.x, lane = tid & 63, wv = tid >> 6;
  const int wm = wv >> 1, wn = wv & 1;
  const int m0 = blockIdx.x * BM, n0 = blockIdx.y * BN;

  f32x4 acc[MI][NI];
  #pragma unroll
  for(int i = 0; i < MI; i++)
    #pragma unroll
    for(int j = 0; j < NI; j++) acc[i][j] = (f32x4)(0.f);

  const int rowS = tid >> 2;
  const int colb = (tid & 3) * 16;

  auto stage = [&](int buf, int k0){
    #pragma unroll
    for(int p = 0; p < PA; p++){
      const int h = p / RPA, rb = (p % RPA) * 64;
      const char* g = (const char*)(A + (size_t)(m0 + rb + rowS) * K + k0 + h * 32) + colb;
      gld_lds16(g, (char*)sA[buf] + p * 4096 + tid * 16);
    }
    #pragma unroll
    for(int p = 0; p < PB; p++){
      const int h = p / RPB, rb = (p % RPB) * 64;
      const char* g = (const char*)(W + (size_t)(n0 + rb + rowS) * K + k0 + h * 32) + colb;
      gld_lds16(g, (char*)sB[buf] + p * 4096 + tid * 16);
    }
  };

  const int NT = K / BK;
  stage(0, 0);
  __syncthreads();
  int cur = 0;
  for(int t = 0; t < NT; ++t){
    if(t + 1 < NT) stage(cur ^ 1, (t + 1) * BK);
    short8 af[MI][KS], bfr[NI][KS];
    const int kof = (lane >> 4) * 8;
    #pragma unroll
    for(int mi = 0; mi < MI; mi++)
      #pragma unroll
      for(int ks = 0; ks < KS; ks++)
        af[mi][ks] = *(const short8*)(sA[cur] + ks * (BM * 32)
                       + (wm * (BM / 2) + mi * 16 + (lane & 15)) * 32 + kof);
    #pragma unroll
    for(int ni = 0; ni < NI; ni++)
      #pragma unroll
      for(int ks = 0; ks < KS; ks++)
        bfr[ni][ks] = *(const short8*)(sB[cur] + ks * (BN * 32)
                       + (wn * (BN / 2) + ni * 16 + (lane & 15)) * 32 + kof);
    #pragma unroll
    for(int mi = 0; mi < MI; mi++)
      #pragma unroll
      for(int ni = 0; ni < NI; ni++)
        #pragma unroll
        for(int ks = 0; ks < KS; ks++)
          acc[mi][ni] = __builtin_amdgcn_mfma_f32_16x16x32_bf16(af[mi][ks], bfr[ni][ks], acc[mi][ni], 0, 0, 0);
    __syncthreads();
    cur ^= 1;
  }

  const int r0 = m0 + wm * (BM / 2) + (lane >> 4) * 4;
  const int c0 = n0 + wn * (BN / 2) + (lane & 15);
  #pragma unroll
  for(int mi = 0; mi < MI; mi++)
    #pragma unroll
    for(int ni = 0; ni < NI; ni++){
      int cc = c0 + ni * 16;
      float bi = bias[cc];
      #pragma unroll
      for(int j = 0; j < 4; j++){
        int rr = r0 + mi * 16 + j;
        float v = acc[mi][ni][j] + bi;
        if constexpr(EPI == 0){
          float u = v + 0.044715f * v * v * v;
          float gl = v / (1.f + __expf(-1.5957691216f * u));
          ((unsigned short*)outp)[(size_t)rr * N + cc] = f2bf(gl);
        } else {
          v += resx[(size_t)rr * N + cc] + resrow[((rr >> 10) << 9) + cc];
          ((float*)outp)[(size_t)rr * N + cc] = v;
        }
      }
    }
}

// ---------------------------------------------------------------------------
extern "C" void kernel_launch(void* const* d_in, const int* in_sizes, int n_in,
                              void* d_out, int out_size, void* d_ws, size_t ws_size,
                              hipStream_t stream)
{
  (void)in_sizes; (void)n_in; (void)out_size; (void)ws_size;
  const float* x    = (const float*)d_in[0];
  const float* ln1w = (const float*)d_in[1];
  const float* ln1b = (const float*)d_in[2];
  const float* qkvw = (const float*)d_in[3];
  const float* qkvb = (const float*)d_in[4];
  const float* outw = (const float*)d_in[5];
  const float* outb = (const float*)d_in[6];
  const float* ln2w = (const float*)d_in[7];
  const float* ln2b = (const float*)d_in[8];
  const float* fc1w = (const float*)d_in[9];
  const float* fc1b = (const float*)d_in[10];
  const float* fc2w = (const float*)d_in[11];
  const float* fc2b = (const float*)d_in[12];

  char* ws = (char*)d_ws;
  float*          part   = (float*)ws;                            // 512 KB
  float*          vmean  = (float*)(ws + (1u << 19));             // 8 KB
  float*          arow   = (float*)(ws + (1u << 19) + 8192);      // 8 KB
  unsigned short* xl2    = (unsigned short*)(ws + (1u << 20));    // 4 MB
  unsigned short* w1b    = (unsigned short*)(ws + (5u << 20));    // 2 MB
  unsigned short* w2b    = (unsigned short*)(ws + (7u << 20));    // 2 MB
  unsigned short* hact   = (unsigned short*)(ws + (9u << 20));    // 16 MB

  prep<<<2304, 256, 0, stream>>>(x, ln1w, ln1b, fc1w, fc2w, part, w1b, w2b);

  {
    void* args[] = {
      (void*)&part, (void*)&qkvw, (void*)&qkvb, (void*)&outw, (void*)&outb,
      (void*)&x, (void*)&ln2w, (void*)&ln2b,
      (void*)&vmean, (void*)&arow, (void*)&xl2
    };
    hipLaunchCooperativeKernel((void*)attn_mid, dim3(1024), dim3(256),
                               args, 0, stream);
  }

  // fc1 + gelu -> hact (bf16)
  gemm_bt<128, 128, 64, 0><<<dim3(32, 16), 256, 0, stream>>>(
      xl2, w1b, fc1b, nullptr, nullptr, hact, 4096, 2048, 512);
  // fc2 + bias + x + arow -> d_out (f32)
  gemm_bt<64, 64, 128, 1><<<dim3(64, 8), 256, 0, stream>>>(
      hact, w2b, fc2b, x, arow, d_out, 4096, 512, 2048);
}

// Round 10
// 88.768 us; speedup vs baseline: 3.1548x; 3.1548x over previous
//
#include <hip/hip_runtime.h>
#include <hip/hip_bf16.h>
#include <math.h>

#define EPSLN 1e-5f

typedef __attribute__((ext_vector_type(8))) short short8;
typedef __attribute__((ext_vector_type(4))) float f32x4;
typedef __attribute__((ext_vector_type(4))) unsigned short u16x4;

__device__ inline unsigned short f2bf(float f){
  unsigned int u = __float_as_uint(f);
  u += 0x7fffu + ((u >> 16) & 1u);
  return (unsigned short)(u >> 16);
}

// butterfly: all 64 lanes end with the total
__device__ inline float wredb(float v){
  #pragma unroll
  for(int o = 1; o < 64; o <<= 1) v += __shfl_xor(v, o, 64);
  return v;
}

// plain tree reduce, lane 0 has result
__device__ inline float wred(float v){
  #pragma unroll
  for(int o = 32; o > 0; o >>= 1) v += __shfl_down(v, o, 64);
  return v;
}

// ---------------------------------------------------------------------------
// K_A "prep": blocks [0,256): LN1 colsum partial per block -> part[blk][512]
//             blocks [256,2304): f32->bf16 conversion of fc1_w, fc2_w
// ---------------------------------------------------------------------------
__global__ __launch_bounds__(256) void prep(
    const float* __restrict__ x, const float* __restrict__ ln1w,
    const float* __restrict__ ln1b, const float* __restrict__ fc1w,
    const float* __restrict__ fc2w, float* __restrict__ part,
    unsigned short* __restrict__ w1b, unsigned short* __restrict__ w2b)
{
  __shared__ float red[4][512];
  const int tid = threadIdx.x;
  const int blk = blockIdx.x;
  if(blk < 256){
    const int lane = tid & 63, wv = tid >> 6;
    const int b = blk >> 6, local = blk & 63;
    const f32x4* wp = (const f32x4*)ln1w;
    const f32x4* bp = (const f32x4*)ln1b;
    f32x4 w1 = wp[lane * 2], w2 = wp[lane * 2 + 1];
    f32x4 b1 = bp[lane * 2], b2 = bp[lane * 2 + 1];
    f32x4 a1 = (f32x4)(0.f), a2 = (f32x4)(0.f);
    const int r0 = local * 16 + wv * 4;
    for(int i = 0; i < 4; i++){
      const size_t row = (size_t)b * 1024 + r0 + i;
      const f32x4* xr = (const f32x4*)(x + row * 512);
      f32x4 v1 = xr[lane * 2], v2 = xr[lane * 2 + 1];
      float s = v1[0]+v1[1]+v1[2]+v1[3] + v2[0]+v2[1]+v2[2]+v2[3];
      float q = v1[0]*v1[0]+v1[1]*v1[1]+v1[2]*v1[2]+v1[3]*v1[3]
              + v2[0]*v2[0]+v2[1]*v2[1]+v2[2]*v2[2]+v2[3]*v2[3];
      s = wredb(s); q = wredb(q);
      float mu = s * (1.f / 512.f);
      float rs = rsqrtf(q * (1.f / 512.f) - mu * mu + EPSLN);
      #pragma unroll
      for(int j = 0; j < 4; j++){
        a1[j] += (v1[j] - mu) * rs * w1[j] + b1[j];
        a2[j] += (v2[j] - mu) * rs * w2[j] + b2[j];
      }
    }
    #pragma unroll
    for(int j = 0; j < 4; j++){
      red[wv][lane * 8 + j]     = a1[j];
      red[wv][lane * 8 + 4 + j] = a2[j];
    }
    __syncthreads();
    #pragma unroll
    for(int c = tid; c < 512; c += 256)
      part[(size_t)blk * 512 + c] = red[0][c] + red[1][c] + red[2][c] + red[3][c];
  } else {
    const int w = blk - 256;
    const float* src = (w < 1024) ? fc1w : fc2w;
    unsigned short* dst = (w < 1024) ? w1b : w2b;
    const int off = ((w & 1023) << 10) + tid * 4;
    f32x4 v = *(const f32x4*)(src + off);
    u16x4 r;
    #pragma unroll
    for(int j = 0; j < 4; j++) r[j] = f2bf(v[j]);
    *(u16x4*)(dst + off) = r;
  }
}

// ---------------------------------------------------------------------------
// K_B "colsum_matvec": 128 blocks (32/batch). Reduce 64 partials -> cs[512]
// in LDS, then 16 outputs/block: vmean[b,n] = cs.Wv[n]/1024 + bv[n]
// ---------------------------------------------------------------------------
__global__ __launch_bounds__(256) void colsum_matvec(
    const float* __restrict__ part, const float* __restrict__ qkvw,
    const float* __restrict__ qkvb, float* __restrict__ vmean)
{
  __shared__ float cs[512];
  const int tid = threadIdx.x, lane = tid & 63, wv = tid >> 6;
  const int b = blockIdx.x >> 5;
  const int nb = (blockIdx.x & 31) * 16;
  #pragma unroll
  for(int c = tid; c < 512; c += 256){
    float s = 0.f;
    const float* pp = part + (size_t)(b * 64) * 512 + c;
    #pragma unroll 8
    for(int p = 0; p < 64; p++) s += pp[(size_t)p * 512];
    cs[c] = s;
  }
  __syncthreads();
  const f32x4* c4 = (const f32x4*)cs;
  f32x4 v1 = c4[lane * 2], v2 = c4[lane * 2 + 1];
  #pragma unroll
  for(int o = 0; o < 4; o++){
    int n = nb + wv * 4 + o;
    const f32x4* wr = (const f32x4*)(qkvw + (size_t)(1024 + n) * 512);
    f32x4 w1 = wr[lane * 2], w2 = wr[lane * 2 + 1];
    float s = 0.f;
    #pragma unroll
    for(int i = 0; i < 4; i++) s += v1[i] * w1[i] + v2[i] * w2[i];
    s = wred(s);
    if(lane == 0) vmean[b * 512 + n] = s * (1.f / 1024.f) + qkvb[1024 + n];
  }
}

// ---------------------------------------------------------------------------
// K_C: arow[b,n] = vmean[b].outw[n] + outb[n]   (wave per output, 512 blocks)
// ---------------------------------------------------------------------------
__global__ __launch_bounds__(256) void matvec512(
    const float* __restrict__ vec, const float* __restrict__ Wm,
    const float* __restrict__ bias, float* __restrict__ outv)
{
  int gw = blockIdx.x * 4 + (threadIdx.x >> 6);
  int lane = threadIdx.x & 63;
  int b = gw >> 9, n = gw & 511;
  const f32x4* vr = (const f32x4*)(vec + ((size_t)b << 9));
  const f32x4* wr = (const f32x4*)(Wm + ((size_t)n << 9));
  f32x4 v1 = vr[lane * 2], v2 = vr[lane * 2 + 1];
  f32x4 w1 = wr[lane * 2], w2 = wr[lane * 2 + 1];
  float s = 0.f;
  #pragma unroll
  for(int i = 0; i < 4; i++) s += v1[i] * w1[i] + v2[i] * w2[i];
  s = wred(s);
  if(lane == 0) outv[gw] = s + bias[n];
}

// ---------------------------------------------------------------------------
// K_D: xl2 = LN2(x + arow) as bf16. Wave-per-row. grid 1024.
// ---------------------------------------------------------------------------
__global__ __launch_bounds__(256) void add_ln2(
    const float* __restrict__ x, const float* __restrict__ arow,
    const float* __restrict__ w, const float* __restrict__ bb,
    unsigned short* __restrict__ xl2)
{
  const int tid = threadIdx.x, lane = tid & 63, wv = tid >> 6;
  const size_t row = (size_t)blockIdx.x * 4 + wv;
  const int b = (int)(row >> 10);
  const f32x4* xr = (const f32x4*)(x + row * 512);
  const f32x4* ar = (const f32x4*)(arow + ((size_t)b << 9));
  f32x4 v1 = xr[lane * 2], v2 = xr[lane * 2 + 1];
  f32x4 r1 = ar[lane * 2], r2 = ar[lane * 2 + 1];
  #pragma unroll
  for(int j = 0; j < 4; j++){ v1[j] += r1[j]; v2[j] += r2[j]; }
  float s = v1[0]+v1[1]+v1[2]+v1[3] + v2[0]+v2[1]+v2[2]+v2[3];
  float q = v1[0]*v1[0]+v1[1]*v1[1]+v1[2]*v1[2]+v1[3]*v1[3]
          + v2[0]*v2[0]+v2[1]*v2[1]+v2[2]*v2[2]+v2[3]*v2[3];
  s = wredb(s); q = wredb(q);
  float mu = s * (1.f / 512.f);
  float rs = rsqrtf(q * (1.f / 512.f) - mu * mu + EPSLN);
  const f32x4* wp = (const f32x4*)w;
  const f32x4* bp = (const f32x4*)bb;
  f32x4 w1 = wp[lane * 2], w2 = wp[lane * 2 + 1];
  f32x4 b1 = bp[lane * 2], b2 = bp[lane * 2 + 1];
  u16x4 o1, o2;
  #pragma unroll
  for(int j = 0; j < 4; j++){
    o1[j] = f2bf((v1[j] - mu) * rs * w1[j] + b1[j]);
    o2[j] = f2bf((v2[j] - mu) * rs * w2[j] + b2[j]);
  }
  u16x4* op = (u16x4*)(xl2 + row * 512 + lane * 8);
  op[0] = o1; op[1] = o2;
}

// ---------------------------------------------------------------------------
// K_E/K_F: bf16 MFMA GEMM. A staged via LDS (double-buffered, layout
// [BK/32 k-slices][rows][32 shorts]); B (weights, 2MB, L2-resident) read
// DIRECTLY from global into registers, software-pipelined one K-step ahead
// (manually 2x-unrolled loop, static reg names). Halves LDS traffic and
// staging volume; MFMA:ds_read ratio doubles.
// 4 waves 2x2; wave tile (BM/2) x (BN/2); MI=BM/32, NI=BN/32.
// EPI==0: gelu -> bf16 ; EPI==1: + resx + resrow -> f32
// ---------------------------------------------------------------------------
__device__ inline void gld_lds16(const void* g, void* l){
  __builtin_amdgcn_global_load_lds(
      (const __attribute__((address_space(1))) void*)g,
      (__attribute__((address_space(3))) void*)l, 16, 0, 0);
}

template<int BM, int BN, int BK, int EPI>
__global__ __launch_bounds__(256, 2) void gemm_bt(
    const unsigned short* __restrict__ A, const unsigned short* __restrict__ W,
    const float* __restrict__ bias, const float* __restrict__ resx,
    const float* __restrict__ resrow, void* __restrict__ outp,
    int M, int N, int K)
{
  constexpr int MI = BM / 32, NI = BN / 32;
  constexpr int KS = BK / 32;                    // k-slices of 32
  constexpr int PA = BM * BK / 2048;             // A staging passes (4KB each)
  constexpr int RPA = BM / 64;                   // 64-row chunks per k-slice
  __shared__ __align__(16) unsigned short sA[2][BM * BK];
  const int tid = threadIdx.x, lane = tid & 63, wv = tid >> 6;
  const int wm = wv >> 1, wn = wv & 1;
  const int m0 = blockIdx.x * BM, n0 = blockIdx.y * BN;

  f32x4 acc[MI][NI];
  #pragma unroll
  for(int i = 0; i < MI; i++)
    #pragma unroll
    for(int j = 0; j < NI; j++) acc[i][j] = (f32x4)(0.f);

  const int rowS = tid >> 2;
  const int colb = (tid & 3) * 16;
  const int kof  = (lane >> 4) * 8;

  // per-lane B row base (points at this lane's fragment row, k-chunk offset)
  const unsigned short* Wl = W + (size_t)(n0 + wn * (BN / 2) + (lane & 15)) * K + kof;

  auto stageA = [&](int buf, int k0){
    #pragma unroll
    for(int p = 0; p < PA; p++){
      const int h = p / RPA, rb = (p % RPA) * 64;
      const char* g = (const char*)(A + (size_t)(m0 + rb + rowS) * K + k0 + h * 32) + colb;
      gld_lds16(g, (char*)sA[buf] + p * 4096 + tid * 16);
    }
  };

  auto loadB = [&](short8 (&br)[NI][KS], int k0){
    #pragma unroll
    for(int ni = 0; ni < NI; ni++)
      #pragma unroll
      for(int ks = 0; ks < KS; ks++)
        br[ni][ks] = *(const short8*)(Wl + (size_t)ni * 16 * K + k0 + ks * 32);
  };

  auto compute = [&](const unsigned short* sAc, short8 (&br)[NI][KS]){
    short8 af[MI][KS];
    #pragma unroll
    for(int mi = 0; mi < MI; mi++)
      #pragma unroll
      for(int ks = 0; ks < KS; ks++)
        af[mi][ks] = *(const short8*)(sAc + ks * (BM * 32)
                       + (wm * (BM / 2) + mi * 16 + (lane & 15)) * 32 + kof);
    #pragma unroll
    for(int mi = 0; mi < MI; mi++)
      #pragma unroll
      for(int ni = 0; ni < NI; ni++)
        #pragma unroll
        for(int ks = 0; ks < KS; ks++)
          acc[mi][ni] = __builtin_amdgcn_mfma_f32_16x16x32_bf16(
              af[mi][ks], br[ni][ks], acc[mi][ni], 0, 0, 0);
  };

  const int NT = K / BK;      // always even here (8 or 16)
  short8 b0[NI][KS], b1[NI][KS];
  stageA(0, 0);
  loadB(b0, 0);
  __syncthreads();            // drains stageA + b0
  for(int t = 0; t < NT; t += 2){
    // step t: sA[0], b0
    if(t + 1 < NT){ stageA(1, (t + 1) * BK); loadB(b1, (t + 1) * BK); }
    compute(sA[0], b0);
    __syncthreads();
    // step t+1: sA[1], b1
    if(t + 2 < NT){ stageA(0, (t + 2) * BK); loadB(b0, (t + 2) * BK); }
    compute(sA[1], b1);
    __syncthreads();
  }

  const int r0 = m0 + wm * (BM / 2) + (lane >> 4) * 4;
  const int c0 = n0 + wn * (BN / 2) + (lane & 15);
  #pragma unroll
  for(int mi = 0; mi < MI; mi++)
    #pragma unroll
    for(int ni = 0; ni < NI; ni++){
      int cc = c0 + ni * 16;
      float bi = bias[cc];
      #pragma unroll
      for(int j = 0; j < 4; j++){
        int rr = r0 + mi * 16 + j;
        float v = acc[mi][ni][j] + bi;
        if constexpr(EPI == 0){
          float u = v + 0.044715f * v * v * v;
          float gl = v / (1.f + __expf(-1.5957691216f * u));
          ((unsigned short*)outp)[(size_t)rr * N + cc] = f2bf(gl);
        } else {
          v += resx[(size_t)rr * N + cc] + resrow[((rr >> 10) << 9) + cc];
          ((float*)outp)[(size_t)rr * N + cc] = v;
        }
      }
    }
}

// ---------------------------------------------------------------------------
extern "C" void kernel_launch(void* const* d_in, const int* in_sizes, int n_in,
                              void* d_out, int out_size, void* d_ws, size_t ws_size,
                              hipStream_t stream)
{
  (void)in_sizes; (void)n_in; (void)out_size; (void)ws_size;
  const float* x    = (const float*)d_in[0];
  const float* ln1w = (const float*)d_in[1];
  const float* ln1b = (const float*)d_in[2];
  const float* qkvw = (const float*)d_in[3];
  const float* qkvb = (const float*)d_in[4];
  const float* outw = (const float*)d_in[5];
  const float* outb = (const float*)d_in[6];
  const float* ln2w = (const float*)d_in[7];
  const float* ln2b = (const float*)d_in[8];
  const float* fc1w = (const float*)d_in[9];
  const float* fc1b = (const float*)d_in[10];
  const float* fc2w = (const float*)d_in[11];
  const float* fc2b = (const float*)d_in[12];

  char* ws = (char*)d_ws;
  float*          part   = (float*)ws;                            // 512 KB
  float*          vmean  = (float*)(ws + (1u << 19));             // 8 KB
  float*          arow   = (float*)(ws + (1u << 19) + 8192);      // 8 KB
  unsigned short* xl2    = (unsigned short*)(ws + (1u << 20));    // 4 MB
  unsigned short* w1b    = (unsigned short*)(ws + (5u << 20));    // 2 MB
  unsigned short* w2b    = (unsigned short*)(ws + (7u << 20));    // 2 MB
  unsigned short* hact   = (unsigned short*)(ws + (9u << 20));    // 16 MB

  prep<<<2304, 256, 0, stream>>>(x, ln1w, ln1b, fc1w, fc2w, part, w1b, w2b);
  colsum_matvec<<<128, 256, 0, stream>>>(part, qkvw, qkvb, vmean);
  matvec512<<<512, 256, 0, stream>>>(vmean, outw, outb, arow);
  add_ln2<<<1024, 256, 0, stream>>>(x, arow, ln2w, ln2b, xl2);
  // fc1 + gelu -> hact (bf16)
  gemm_bt<128, 128, 64, 0><<<dim3(32, 16), 256, 0, stream>>>(
      xl2, w1b, fc1b, nullptr, nullptr, hact, 4096, 2048, 512);
  // fc2 + bias + x + arow -> d_out (f32)
  gemm_bt<64, 64, 128, 1><<<dim3(64, 8), 256, 0, stream>>>(
      hact, w2b, fc2b, x, arow, d_out, 4096, 512, 2048);
}

// Round 11
// 62.817 us; speedup vs baseline: 4.4581x; 1.4131x over previous
//
#include <hip/hip_runtime.h>
#include <hip/hip_bf16.h>
#include <math.h>

#define EPSLN 1e-5f

typedef __attribute__((ext_vector_type(8))) short short8;
typedef __attribute__((ext_vector_type(4))) float f32x4;
typedef __attribute__((ext_vector_type(4))) unsigned short u16x4;

__device__ inline unsigned short f2bf(float f){
  unsigned int u = __float_as_uint(f);
  u += 0x7fffu + ((u >> 16) & 1u);
  return (unsigned short)(u >> 16);
}

// butterfly: all 64 lanes end with the total
__device__ inline float wredb(float v){
  #pragma unroll
  for(int o = 1; o < 64; o <<= 1) v += __shfl_xor(v, o, 64);
  return v;
}

// plain tree reduce, lane 0 has result
__device__ inline float wred(float v){
  #pragma unroll
  for(int o = 32; o > 0; o >>= 1) v += __shfl_down(v, o, 64);
  return v;
}

// ---------------------------------------------------------------------------
// K_A "prep": blocks [0,256): LN1 colsum partial per block -> part[blk][512]
//             blocks [256,2304): f32->bf16 conversion of fc1_w, fc2_w
// ---------------------------------------------------------------------------
__global__ __launch_bounds__(256) void prep(
    const float* __restrict__ x, const float* __restrict__ ln1w,
    const float* __restrict__ ln1b, const float* __restrict__ fc1w,
    const float* __restrict__ fc2w, float* __restrict__ part,
    unsigned short* __restrict__ w1b, unsigned short* __restrict__ w2b)
{
  __shared__ float red[4][512];
  const int tid = threadIdx.x;
  const int blk = blockIdx.x;
  if(blk < 256){
    const int lane = tid & 63, wv = tid >> 6;
    const int b = blk >> 6, local = blk & 63;
    const f32x4* wp = (const f32x4*)ln1w;
    const f32x4* bp = (const f32x4*)ln1b;
    f32x4 w1 = wp[lane * 2], w2 = wp[lane * 2 + 1];
    f32x4 b1 = bp[lane * 2], b2 = bp[lane * 2 + 1];
    f32x4 a1 = (f32x4)(0.f), a2 = (f32x4)(0.f);
    const int r0 = local * 16 + wv * 4;
    for(int i = 0; i < 4; i++){
      const size_t row = (size_t)b * 1024 + r0 + i;
      const f32x4* xr = (const f32x4*)(x + row * 512);
      f32x4 v1 = xr[lane * 2], v2 = xr[lane * 2 + 1];
      float s = v1[0]+v1[1]+v1[2]+v1[3] + v2[0]+v2[1]+v2[2]+v2[3];
      float q = v1[0]*v1[0]+v1[1]*v1[1]+v1[2]*v1[2]+v1[3]*v1[3]
              + v2[0]*v2[0]+v2[1]*v2[1]+v2[2]*v2[2]+v2[3]*v2[3];
      s = wredb(s); q = wredb(q);
      float mu = s * (1.f / 512.f);
      float rs = rsqrtf(q * (1.f / 512.f) - mu * mu + EPSLN);
      #pragma unroll
      for(int j = 0; j < 4; j++){
        a1[j] += (v1[j] - mu) * rs * w1[j] + b1[j];
        a2[j] += (v2[j] - mu) * rs * w2[j] + b2[j];
      }
    }
    #pragma unroll
    for(int j = 0; j < 4; j++){
      red[wv][lane * 8 + j]     = a1[j];
      red[wv][lane * 8 + 4 + j] = a2[j];
    }
    __syncthreads();
    #pragma unroll
    for(int c = tid; c < 512; c += 256)
      part[(size_t)blk * 512 + c] = red[0][c] + red[1][c] + red[2][c] + red[3][c];
  } else {
    const int w = blk - 256;
    const float* src = (w < 1024) ? fc1w : fc2w;
    unsigned short* dst = (w < 1024) ? w1b : w2b;
    const int off = ((w & 1023) << 10) + tid * 4;
    f32x4 v = *(const f32x4*)(src + off);
    u16x4 r;
    #pragma unroll
    for(int j = 0; j < 4; j++) r[j] = f2bf(v[j]);
    *(u16x4*)(dst + off) = r;
  }
}

// ---------------------------------------------------------------------------
// K_B "colsum_matvec": 128 blocks (32/batch). Reduce 64 partials -> cs[512]
// in LDS, then 16 outputs/block: vmean[b,n] = cs.Wv[n]/1024 + bv[n]
// ---------------------------------------------------------------------------
__global__ __launch_bounds__(256) void colsum_matvec(
    const float* __restrict__ part, const float* __restrict__ qkvw,
    const float* __restrict__ qkvb, float* __restrict__ vmean)
{
  __shared__ float cs[512];
  const int tid = threadIdx.x, lane = tid & 63, wv = tid >> 6;
  const int b = blockIdx.x >> 5;
  const int nb = (blockIdx.x & 31) * 16;
  #pragma unroll
  for(int c = tid; c < 512; c += 256){
    float s = 0.f;
    const float* pp = part + (size_t)(b * 64) * 512 + c;
    #pragma unroll 8
    for(int p = 0; p < 64; p++) s += pp[(size_t)p * 512];
    cs[c] = s;
  }
  __syncthreads();
  const f32x4* c4 = (const f32x4*)cs;
  f32x4 v1 = c4[lane * 2], v2 = c4[lane * 2 + 1];
  #pragma unroll
  for(int o = 0; o < 4; o++){
    int n = nb + wv * 4 + o;
    const f32x4* wr = (const f32x4*)(qkvw + (size_t)(1024 + n) * 512);
    f32x4 w1 = wr[lane * 2], w2 = wr[lane * 2 + 1];
    float s = 0.f;
    #pragma unroll
    for(int i = 0; i < 4; i++) s += v1[i] * w1[i] + v2[i] * w2[i];
    s = wred(s);
    if(lane == 0) vmean[b * 512 + n] = s * (1.f / 1024.f) + qkvb[1024 + n];
  }
}

// ---------------------------------------------------------------------------
// K_C: arow[b,n] = vmean[b].outw[n] + outb[n]   (wave per output, 512 blocks)
// ---------------------------------------------------------------------------
__global__ __launch_bounds__(256) void matvec512(
    const float* __restrict__ vec, const float* __restrict__ Wm,
    const float* __restrict__ bias, float* __restrict__ outv)
{
  int gw = blockIdx.x * 4 + (threadIdx.x >> 6);
  int lane = threadIdx.x & 63;
  int b = gw >> 9, n = gw & 511;
  const f32x4* vr = (const f32x4*)(vec + ((size_t)b << 9));
  const f32x4* wr = (const f32x4*)(Wm + ((size_t)n << 9));
  f32x4 v1 = vr[lane * 2], v2 = vr[lane * 2 + 1];
  f32x4 w1 = wr[lane * 2], w2 = wr[lane * 2 + 1];
  float s = 0.f;
  #pragma unroll
  for(int i = 0; i < 4; i++) s += v1[i] * w1[i] + v2[i] * w2[i];
  s = wred(s);
  if(lane == 0) outv[gw] = s + bias[n];
}

// ---------------------------------------------------------------------------
// K_D: xl2 = LN2(x + arow) as bf16. Wave-per-row. grid 1024.
// ---------------------------------------------------------------------------
__global__ __launch_bounds__(256) void add_ln2(
    const float* __restrict__ x, const float* __restrict__ arow,
    const float* __restrict__ w, const float* __restrict__ bb,
    unsigned short* __restrict__ xl2)
{
  const int tid = threadIdx.x, lane = tid & 63, wv = tid >> 6;
  const size_t row = (size_t)blockIdx.x * 4 + wv;
  const int b = (int)(row >> 10);
  const f32x4* xr = (const f32x4*)(x + row * 512);
  const f32x4* ar = (const f32x4*)(arow + ((size_t)b << 9));
  f32x4 v1 = xr[lane * 2], v2 = xr[lane * 2 + 1];
  f32x4 r1 = ar[lane * 2], r2 = ar[lane * 2 + 1];
  #pragma unroll
  for(int j = 0; j < 4; j++){ v1[j] += r1[j]; v2[j] += r2[j]; }
  float s = v1[0]+v1[1]+v1[2]+v1[3] + v2[0]+v2[1]+v2[2]+v2[3];
  float q = v1[0]*v1[0]+v1[1]*v1[1]+v1[2]*v1[2]+v1[3]*v1[3]
          + v2[0]*v2[0]+v2[1]*v2[1]+v2[2]*v2[2]+v2[3]*v2[3];
  s = wredb(s); q = wredb(q);
  float mu = s * (1.f / 512.f);
  float rs = rsqrtf(q * (1.f / 512.f) - mu * mu + EPSLN);
  const f32x4* wp = (const f32x4*)w;
  const f32x4* bp = (const f32x4*)bb;
  f32x4 w1 = wp[lane * 2], w2 = wp[lane * 2 + 1];
  f32x4 b1 = bp[lane * 2], b2 = bp[lane * 2 + 1];
  u16x4 o1, o2;
  #pragma unroll
  for(int j = 0; j < 4; j++){
    o1[j] = f2bf((v1[j] - mu) * rs * w1[j] + b1[j]);
    o2[j] = f2bf((v2[j] - mu) * rs * w2[j] + b2[j]);
  }
  u16x4* op = (u16x4*)(xl2 + row * 512 + lane * 8);
  op[0] = o1; op[1] = o2;
}

// ---------------------------------------------------------------------------
// K_E/K_F: bf16 MFMA GEMM, 2-phase double-buffered, parametric BK.
// LDS layout per matrix: [BK/32 k-slices][rows][32 shorts].
// 4 waves 2x2; wave tile (BM/2) x (BN/2); MI=BM/32, NI=BN/32.
// EPI==0: gelu -> bf16 ; EPI==1: + resx + resrow -> f32
// ---------------------------------------------------------------------------
__device__ inline void gld_lds16(const void* g, void* l){
  __builtin_amdgcn_global_load_lds(
      (const __attribute__((address_space(1))) void*)g,
      (__attribute__((address_space(3))) void*)l, 16, 0, 0);
}

template<int BM, int BN, int BK, int EPI>
__global__ __launch_bounds__(256, 2) void gemm_bt(
    const unsigned short* __restrict__ A, const unsigned short* __restrict__ W,
    const float* __restrict__ bias, const float* __restrict__ resx,
    const float* __restrict__ resrow, void* __restrict__ outp,
    int M, int N, int K)
{
  constexpr int MI = BM / 32, NI = BN / 32;
  constexpr int KS = BK / 32;                    // k-slices of 32
  constexpr int PA = BM * BK / 2048;             // staging passes (4KB each)
  constexpr int PB = BN * BK / 2048;
  constexpr int RPA = BM / 64, RPB = BN / 64;    // 64-row chunks per k-slice
  __shared__ __align__(16) unsigned short sA[2][BM * BK];
  __shared__ __align__(16) unsigned short sB[2][BN * BK];
  const int tid = threadIdx.x, lane = tid & 63, wv = tid >> 6;
  const int wm = wv >> 1, wn = wv & 1;
  const int m0 = blockIdx.x * BM, n0 = blockIdx.y * BN;

  f32x4 acc[MI][NI];
  #pragma unroll
  for(int i = 0; i < MI; i++)
    #pragma unroll
    for(int j = 0; j < NI; j++) acc[i][j] = (f32x4)(0.f);

  const int rowS = tid >> 2;
  const int colb = (tid & 3) * 16;

  auto stage = [&](int buf, int k0){
    #pragma unroll
    for(int p = 0; p < PA; p++){
      const int h = p / RPA, rb = (p % RPA) * 64;
      const char* g = (const char*)(A + (size_t)(m0 + rb + rowS) * K + k0 + h * 32) + colb;
      gld_lds16(g, (char*)sA[buf] + p * 4096 + tid * 16);
    }
    #pragma unroll
    for(int p = 0; p < PB; p++){
      const int h = p / RPB, rb = (p % RPB) * 64;
      const char* g = (const char*)(W + (size_t)(n0 + rb + rowS) * K + k0 + h * 32) + colb;
      gld_lds16(g, (char*)sB[buf] + p * 4096 + tid * 16);
    }
  };

  const int NT = K / BK;
  stage(0, 0);
  __syncthreads();
  int cur = 0;
  for(int t = 0; t < NT; ++t){
    if(t + 1 < NT) stage(cur ^ 1, (t + 1) * BK);
    short8 af[MI][KS], bfr[NI][KS];
    const int kof = (lane >> 4) * 8;
    #pragma unroll
    for(int mi = 0; mi < MI; mi++)
      #pragma unroll
      for(int ks = 0; ks < KS; ks++)
        af[mi][ks] = *(const short8*)(sA[cur] + ks * (BM * 32)
                       + (wm * (BM / 2) + mi * 16 + (lane & 15)) * 32 + kof);
    #pragma unroll
    for(int ni = 0; ni < NI; ni++)
      #pragma unroll
      for(int ks = 0; ks < KS; ks++)
        bfr[ni][ks] = *(const short8*)(sB[cur] + ks * (BN * 32)
                       + (wn * (BN / 2) + ni * 16 + (lane & 15)) * 32 + kof);
    #pragma unroll
    for(int mi = 0; mi < MI; mi++)
      #pragma unroll
      for(int ni = 0; ni < NI; ni++)
        #pragma unroll
        for(int ks = 0; ks < KS; ks++)
          acc[mi][ni] = __builtin_amdgcn_mfma_f32_16x16x32_bf16(af[mi][ks], bfr[ni][ks], acc[mi][ni], 0, 0, 0);
    __syncthreads();
    cur ^= 1;
  }

  const int r0 = m0 + wm * (BM / 2) + (lane >> 4) * 4;
  const int c0 = n0 + wn * (BN / 2) + (lane & 15);
  #pragma unroll
  for(int mi = 0; mi < MI; mi++)
    #pragma unroll
    for(int ni = 0; ni < NI; ni++){
      int cc = c0 + ni * 16;
      float bi = bias[cc];
      #pragma unroll
      for(int j = 0; j < 4; j++){
        int rr = r0 + mi * 16 + j;
        float v = acc[mi][ni][j] + bi;
        if constexpr(EPI == 0){
          float u = v + 0.044715f * v * v * v;
          float gl = v / (1.f + __expf(-1.5957691216f * u));
          ((unsigned short*)outp)[(size_t)rr * N + cc] = f2bf(gl);
        } else {
          v += resx[(size_t)rr * N + cc] + resrow[((rr >> 10) << 9) + cc];
          ((float*)outp)[(size_t)rr * N + cc] = v;
        }
      }
    }
}

// ---------------------------------------------------------------------------
extern "C" void kernel_launch(void* const* d_in, const int* in_sizes, int n_in,
                              void* d_out, int out_size, void* d_ws, size_t ws_size,
                              hipStream_t stream)
{
  (void)in_sizes; (void)n_in; (void)out_size; (void)ws_size;
  const float* x    = (const float*)d_in[0];
  const float* ln1w = (const float*)d_in[1];
  const float* ln1b = (const float*)d_in[2];
  const float* qkvw = (const float*)d_in[3];
  const float* qkvb = (const float*)d_in[4];
  const float* outw = (const float*)d_in[5];
  const float* outb = (const float*)d_in[6];
  const float* ln2w = (const float*)d_in[7];
  const float* ln2b = (const float*)d_in[8];
  const float* fc1w = (const float*)d_in[9];
  const float* fc1b = (const float*)d_in[10];
  const float* fc2w = (const float*)d_in[11];
  const float* fc2b = (const float*)d_in[12];

  char* ws = (char*)d_ws;
  float*          part   = (float*)ws;                            // 512 KB
  float*          vmean  = (float*)(ws + (1u << 19));             // 8 KB
  float*          arow   = (float*)(ws + (1u << 19) + 8192);      // 8 KB
  unsigned short* xl2    = (unsigned short*)(ws + (1u << 20));    // 4 MB
  unsigned short* w1b    = (unsigned short*)(ws + (5u << 20));    // 2 MB
  unsigned short* w2b    = (unsigned short*)(ws + (7u << 20));    // 2 MB
  unsigned short* hact   = (unsigned short*)(ws + (9u << 20));    // 16 MB

  prep<<<2304, 256, 0, stream>>>(x, ln1w, ln1b, fc1w, fc2w, part, w1b, w2b);
  colsum_matvec<<<128, 256, 0, stream>>>(part, qkvw, qkvb, vmean);
  matvec512<<<512, 256, 0, stream>>>(vmean, outw, outb, arow);
  add_ln2<<<1024, 256, 0, stream>>>(x, arow, ln2w, ln2b, xl2);
  // fc1 + gelu -> hact (bf16)
  gemm_bt<128, 128, 64, 0><<<dim3(32, 16), 256, 0, stream>>>(
      xl2, w1b, fc1b, nullptr, nullptr, hact, 4096, 2048, 512);
  // fc2 + bias + x + arow -> d_out (f32)
  gemm_bt<64, 64, 128, 1><<<dim3(64, 8), 256, 0, stream>>>(
      hact, w2b, fc2b, x, arow, d_out, 4096, 512, 2048);
}